// Round 4
// baseline (356.011 us; speedup 1.0000x reference)
//
#include <hip/hip_runtime.h>

// ImageWiseConv2d: per-sample conv, images [64,64,128,128] f32, kernels [64,64,3,3] f32
// out [64,1,126,126] f32 (VALID, stride 1).
//
// R7: R6 structure (2x4 out/thread, shuffle halo, 4x float4 loads/chan, 256thr, 512blk,
// no LDS/barriers) + PREFETCH DEPTH 4 (was 1).
// Evidence: R6 (-33% bytes, -50% requests) was NEUTRAL vs R3 (354.9 vs 356.7 total)
// -> not bytes/request bound. R5 (2x waves, +50% bytes) regressed -> not simple TLP.
// Remaining fit: per-channel-iteration latency serialization: 96us/64 iters ~ 3600 cyc
// per iter = HBM-latency scale; 1-deep prefetch only covers ~144 cyc with compute.
// Fix: 4 named register sets rotated by hand (static indexing only -- no scratch),
// issue loads for c+4 right after consuming set c%4 -> issue-to-consume distance
// ~3 compute stages (~600 cyc) + cross-wave overlap. Traffic unchanged (~290 MB HBM).
// VGPR: 16 float4 bufs (64) + 8 acc + addr ~= 110, budget 256 at (256,2) -- no spill.
// Prediction: latency-bound -> kernel ~55-65us, total ~315-325. Unchanged -> BW-wall
// for this access pattern; pivot to global_load_lds staging or channel-split.

#define NS   64
#define CCH  64
#define HH   128
#define WW   128
#define OHH  126
#define OWW  126
#define CHS  (HH * WW)   // 16384 floats per channel

// Issue 4 row loads (float4 each) for channel `cidx` into the given register set.
#define ISSUE(Ra, Rb, Rc, Rd, cidx)                                   \
    {                                                                 \
        const float* q_ = p0 + (cidx) * CHS;                          \
        Ra = *(const float4*)(q_);                                    \
        Rb = *(const float4*)(q_ + WW);                               \
        Rc = *(const float4*)(q_ + 2 * WW);                           \
        Rd = *(const float4*)(q_ + 3 * WW);                           \
    }

// Consume one register set: 9 scalar weight loads, 8 halo shuffles, 72 FMAs.
#define STAGE(Ra, Rb, Rc, Rd, cidx)                                                        \
    {                                                                                      \
        const int cc_ = (cidx);                                                            \
        const float w0 = kp[cc_ * 9 + 0], w1 = kp[cc_ * 9 + 1], w2 = kp[cc_ * 9 + 2];      \
        const float w3 = kp[cc_ * 9 + 3], w4 = kp[cc_ * 9 + 4], w5 = kp[cc_ * 9 + 5];      \
        const float w6 = kp[cc_ * 9 + 6], w7 = kp[cc_ * 9 + 7], w8 = kp[cc_ * 9 + 8];      \
        const float h4a = __shfl_down(Ra.x, 1), h5a = __shfl_down(Ra.y, 1);                 \
        const float h4b = __shfl_down(Rb.x, 1), h5b = __shfl_down(Rb.y, 1);                 \
        const float h4c = __shfl_down(Rc.x, 1), h5c = __shfl_down(Rc.y, 1);                 \
        const float h4d = __shfl_down(Rd.x, 1), h5d = __shfl_down(Rd.y, 1);                 \
        {                                                                                  \
            const float v0 = Ra.x, v1 = Ra.y, v2 = Ra.z, v3 = Ra.w, v4 = h4a, v5 = h5a;    \
            a00 = fmaf(w0, v0, a00); a00 = fmaf(w1, v1, a00); a00 = fmaf(w2, v2, a00);     \
            a01 = fmaf(w0, v1, a01); a01 = fmaf(w1, v2, a01); a01 = fmaf(w2, v3, a01);     \
            a02 = fmaf(w0, v2, a02); a02 = fmaf(w1, v3, a02); a02 = fmaf(w2, v4, a02);     \
            a03 = fmaf(w0, v3, a03); a03 = fmaf(w1, v4, a03); a03 = fmaf(w2, v5, a03);     \
        }                                                                                  \
        {                                                                                  \
            const float v0 = Rb.x, v1 = Rb.y, v2 = Rb.z, v3 = Rb.w, v4 = h4b, v5 = h5b;    \
            a00 = fmaf(w3, v0, a00); a00 = fmaf(w4, v1, a00); a00 = fmaf(w5, v2, a00);     \
            a01 = fmaf(w3, v1, a01); a01 = fmaf(w4, v2, a01); a01 = fmaf(w5, v3, a01);     \
            a02 = fmaf(w3, v2, a02); a02 = fmaf(w4, v3, a02); a02 = fmaf(w5, v4, a02);     \
            a03 = fmaf(w3, v3, a03); a03 = fmaf(w4, v4, a03); a03 = fmaf(w5, v5, a03);     \
            a10 = fmaf(w0, v0, a10); a10 = fmaf(w1, v1, a10); a10 = fmaf(w2, v2, a10);     \
            a11 = fmaf(w0, v1, a11); a11 = fmaf(w1, v2, a11); a11 = fmaf(w2, v3, a11);     \
            a12 = fmaf(w0, v2, a12); a12 = fmaf(w1, v3, a12); a12 = fmaf(w2, v4, a12);     \
            a13 = fmaf(w0, v3, a13); a13 = fmaf(w1, v4, a13); a13 = fmaf(w2, v5, a13);     \
        }                                                                                  \
        {                                                                                  \
            const float v0 = Rc.x, v1 = Rc.y, v2 = Rc.z, v3 = Rc.w, v4 = h4c, v5 = h5c;    \
            a00 = fmaf(w6, v0, a00); a00 = fmaf(w7, v1, a00); a00 = fmaf(w8, v2, a00);     \
            a01 = fmaf(w6, v1, a01); a01 = fmaf(w7, v2, a01); a01 = fmaf(w8, v3, a01);     \
            a02 = fmaf(w6, v2, a02); a02 = fmaf(w7, v3, a02); a02 = fmaf(w8, v4, a02);     \
            a03 = fmaf(w6, v3, a03); a03 = fmaf(w7, v4, a03); a03 = fmaf(w8, v5, a03);     \
            a10 = fmaf(w3, v0, a10); a10 = fmaf(w4, v1, a10); a10 = fmaf(w5, v2, a10);     \
            a11 = fmaf(w3, v1, a11); a11 = fmaf(w4, v2, a11); a11 = fmaf(w5, v3, a11);     \
            a12 = fmaf(w3, v2, a12); a12 = fmaf(w4, v3, a12); a12 = fmaf(w5, v4, a12);     \
            a13 = fmaf(w3, v3, a13); a13 = fmaf(w4, v4, a13); a13 = fmaf(w5, v5, a13);     \
        }                                                                                  \
        {                                                                                  \
            const float v0 = Rd.x, v1 = Rd.y, v2 = Rd.z, v3 = Rd.w, v4 = h4d, v5 = h5d;    \
            a10 = fmaf(w6, v0, a10); a10 = fmaf(w7, v1, a10); a10 = fmaf(w8, v2, a10);     \
            a11 = fmaf(w6, v1, a11); a11 = fmaf(w7, v2, a11); a11 = fmaf(w8, v3, a11);     \
            a12 = fmaf(w6, v2, a12); a12 = fmaf(w7, v3, a12); a12 = fmaf(w8, v4, a12);     \
            a13 = fmaf(w6, v3, a13); a13 = fmaf(w7, v4, a13); a13 = fmaf(w8, v5, a13);     \
        }                                                                                  \
    }

__global__ __launch_bounds__(256, 2)
void ImageWiseConv2d_direct(const float* __restrict__ img,
                            const float* __restrict__ ker,
                            float* __restrict__ out)
{
    const int tid = threadIdx.x;
    const int bx  = blockIdx.x;          // 0..511
    const int bt  = bx & 7;              // row tile (16 output rows)
    const int n   = bx >> 3;             // sample
    const int h0  = bt * 16;

    const int r0 = (tid >> 5) << 1;      // patch top output row within tile: 0..14
    const int c0 = (tid & 31) << 2;      // patch left output col: 0..124

    // input rows ihr..ihr+3; clamp so we never read past row 127 (clamped case is
    // bt=7,r0=14 whose outputs are discarded)
    int ihr = h0 + r0;
    if (ihr > HH - 4) ihr = HH - 4;

    const float* p0 = img + (((n * CCH) * HH) + ihr) * WW + c0;
    const float* kp = ker + (n * CCH) * 9;   // block-uniform -> scalar loads

    float a00 = 0.f, a01 = 0.f, a02 = 0.f, a03 = 0.f;
    float a10 = 0.f, a11 = 0.f, a12 = 0.f, a13 = 0.f;

    // 4 rotating register sets, 4 rows each (halo via shfl)
    float4 S0a, S0b, S0c, S0d;
    float4 S1a, S1b, S1c, S1d;
    float4 S2a, S2b, S2c, S2d;
    float4 S3a, S3b, S3c, S3d;

    ISSUE(S0a, S0b, S0c, S0d, 0);
    ISSUE(S1a, S1b, S1c, S1d, 1);
    ISSUE(S2a, S2b, S2c, S2d, 2);
    ISSUE(S3a, S3b, S3c, S3d, 3);

    for (int c = 0; c < CCH; c += 4) {
        STAGE(S0a, S0b, S0c, S0d, c);
        if (c + 4 < CCH) ISSUE(S0a, S0b, S0c, S0d, c + 4);
        STAGE(S1a, S1b, S1c, S1d, c + 1);
        if (c + 5 < CCH) ISSUE(S1a, S1b, S1c, S1d, c + 5);
        STAGE(S2a, S2b, S2c, S2d, c + 2);
        if (c + 6 < CCH) ISSUE(S2a, S2b, S2c, S2d, c + 6);
        STAGE(S3a, S3b, S3c, S3d, c + 3);
        if (c + 7 < CCH) ISSUE(S3a, S3b, S3c, S3d, c + 7);
    }

    // ---- store 2x4 (float2 pairs: out rows are 8B- but not 16B-aligned) ----
    const int oh0 = h0 + r0;
    if (oh0 < OHH) {           // oh0 invalid only for bt=7,r0=14, where oh0+1 is too
        float* o0 = out + (n * OHH + oh0) * OWW + c0;
        float* o1 = o0 + OWW;
        *(float2*)o0 = make_float2(a00, a01);
        *(float2*)o1 = make_float2(a10, a11);
        if (c0 < 124) {
            *(float2*)(o0 + 2) = make_float2(a02, a03);
            *(float2*)(o1 + 2) = make_float2(a12, a13);
        }
    }
}

extern "C" void kernel_launch(void* const* d_in, const int* in_sizes, int n_in,
                              void* d_out, int out_size, void* d_ws, size_t ws_size,
                              hipStream_t stream) {
    const float* img = (const float*)d_in[0];   // [64,64,128,128] f32
    const float* ker = (const float*)d_in[1];   // [64,64,3,3] f32
    float* out = (float*)d_out;                 // [64,1,126,126] f32

    ImageWiseConv2d_direct<<<dim3(NS * 8), dim3(256), 0, stream>>>(img, ker, out);
}